// Round 10
// baseline (361.183 us; speedup 1.0000x reference)
//
#include <hip/hip_runtime.h>
#include <hip/hip_bf16.h>
#include <stdint.h>

// Problem dims
#define Bc 8
#define Sc 256
#define Hc 768
#define Rc 40
#define Tc 80
#define KSc 16
#define KOc 8

// Output offsets (float elements)
#define OUT_SSP 5242880
#define OUT_SVA 5243136
#define OUT_BSP 5243264
#define OUT_BVA 5243520
#define OUT_FSP 5243648
#define OUT_FVA 5325568
#define OUT_WSP 5366528
#define OUT_WVA 5448448

// Cm partial stride (p index): 16 groups * Rc * Hc
#define CM_PS (16 * Rc * Hc)
#define BSH (Bc * Sc * Hc)

__device__ inline double wave_reduce_d(double v) {
#pragma unroll
  for (int o = 32; o; o >>= 1) v += __shfl_down(v, o, 64);
  return v;
}
__device__ inline float wave_reduce_f(float v) {
#pragma unroll
  for (int o = 32; o; o >>= 1) v += __shfl_down(v, o, 64);
  return v;
}

// ---------------- prep0: hv (12 blk) + brel (120 blk) ----------------
__global__ __launch_bounds__(256) void k_prep0(const float* __restrict__ brt,
                                               const float* __restrict__ rw,
                                               const float* __restrict__ rb,
                                               const float* __restrict__ Wmats,
                                               const float* __restrict__ head_w,
                                               float* __restrict__ brel,
                                               double* __restrict__ hv) {
  int bb = blockIdx.x;
  int tid = threadIdx.x;
  if (bb < 12) {           // hv_i = h_i + W7^T h_i (f64)
    int idx = bb * 256 + tid;
    int i = idx / Hc, j = idx % Hc;
    const float* h4 = head_w + (4 + i) * Hc;
    const float* W7 = Wmats + (size_t)7 * Hc * Hc;
    double acc = (double)h4[j];
    for (int hh = 0; hh < Hc; ++hh)
      acc += (double)W7[(size_t)hh * Hc + j] * (double)h4[hh];
    hv[idx] = acc;
  } else {                 // brel [R,T]->[R,H]
    int idx = (bb - 12) * 256 + tid;
    int r = idx / Hc, h = idx % Hc;
    float acc = rb[h];
    const float* a = brt + r * Tc;
    const float* w = rw + (size_t)h * Tc;
    for (int t = 0; t < Tc; ++t) acc = fmaf(a[t], w[t], acc);
    brel[idx] = acc;
  }
}

// ---------------- fused l03 + tt: 8 f64 dots per token row ----------------
__global__ __launch_bounds__(256) void k_l03tt(const float* __restrict__ x,
                                               const float* __restrict__ head_w,
                                               const float* __restrict__ head_b,
                                               const double* __restrict__ hv,
                                               float* __restrict__ l03,
                                               double* __restrict__ tt) {
  int bs = blockIdx.x * 4 + (threadIdx.x >> 6);
  int lane = threadIdx.x & 63;
  if (bs >= Bc * Sc) return;
  const float* xr = x + (size_t)bs * Hc;
  double acc[8] = {0, 0, 0, 0, 0, 0, 0, 0};
  for (int h = lane; h < Hc; h += 64) {
    double xv = (double)xr[h];
    acc[0] += xv * (double)head_w[h];
    acc[1] += xv * (double)head_w[Hc + h];
    acc[2] += xv * (double)head_w[2 * Hc + h];
    acc[3] += xv * (double)head_w[3 * Hc + h];
    acc[4] += xv * hv[h];
    acc[5] += xv * hv[Hc + h];
    acc[6] += xv * hv[2 * Hc + h];
    acc[7] += xv * hv[3 * Hc + h];
  }
#pragma unroll
  for (int i = 0; i < 4; ++i) {
    double a = wave_reduce_d(acc[i]);
    if (lane == 0) l03[i * (Bc * Sc) + bs] = (float)(a + (double)head_b[i]);
  }
#pragma unroll
  for (int i = 0; i < 4; ++i) {
    double a = wave_reduce_d(acc[4 + i]);
    if (lane == 0) tt[i * (Bc * Sc) + bs] = a;
  }
}

// ---------------- greedy helpers ----------------
__device__ inline int find_first(const uint64_t* epm, const uint64_t* used, int i) {
  int wi = i >> 6;
  uint64_t m = epm[wi] & ~used[wi] & (~0ull << (i & 63));
  if (m) return (wi << 6) + (__ffsll((unsigned long long)m) - 1);
  for (int w = wi + 1; w < 4; ++w) {
    uint64_t mm = epm[w] & ~used[w];
    if (mm) return (w << 6) + (__ffsll((unsigned long long)mm) - 1);
  }
  return -1;
}

// ---------------- first-level greedy: 16 blocks (dir,b), wave-parallel masks ----------------
__global__ __launch_bounds__(64) void k_greedy1(const float* __restrict__ l03,
                                                int* __restrict__ spans1, int* __restrict__ valid1,
                                                float* __restrict__ out) {
  int t = blockIdx.x;  // 0..15
  int dir = t >> 3, b = t & 7;
  int lane = threadIdx.x;
  const float* sp = l03 + (dir * 2) * (Bc * Sc) + b * Sc;
  const float* ep = sp + Bc * Sc;
  uint64_t spm[4], epm[4];
#pragma unroll
  for (int w = 0; w < 4; ++w) {
    spm[w] = __ballot(sp[w * 64 + lane] > 0.f);
    epm[w] = __ballot(ep[w * 64 + lane] > 0.f);
  }
  __shared__ int ssp0[KSc], ssp1[KSc], sva[KSc];
  if (lane < KSc) { ssp0[lane] = 0; ssp1[lane] = 0; sva[lane] = 0; }
  __syncthreads();
  if (lane == 0) {
    uint64_t used[4] = {0, 0, 0, 0};
    int cnt = 0;
#pragma unroll
    for (int w = 0; w < 4; ++w) {
      uint64_t g = spm[w];
      while (g) {
        int bit = __ffsll((unsigned long long)g) - 1;
        g &= g - 1;
        int i = w * 64 + bit;
        int j = find_first(epm, used, i);
        if (j < 0) continue;
        used[j >> 6] |= (1ull << (j & 63));
        if (cnt < KSc) { ssp0[cnt] = i; ssp1[cnt] = j; sva[cnt] = 1; }
        cnt++;
      }
    }
  }
  __syncthreads();
  int base = (dir * Bc + b) * KSc;
  float* osp = out + (dir ? OUT_BSP : OUT_SSP) + b * KSc * 2;
  float* ova = out + (dir ? OUT_BVA : OUT_SVA) + b * KSc;
  if (lane < KSc) {
    spans1[(base + lane) * 2] = ssp0[lane];
    spans1[(base + lane) * 2 + 1] = ssp1[lane];
    valid1[base + lane] = sva[lane];
    osp[lane * 2] = (float)ssp0[lane];
    osp[lane * 2 + 1] = (float)ssp1[lane];
    ova[lane] = (float)sva[lane];
  }
}

// ---------------- e-gather: eb[row][h] = 0.5*(x[s0]+x[s1]) ----------------
__global__ __launch_bounds__(256) void k_egather(const float* __restrict__ x,
                                                 const int* __restrict__ spans1,
                                                 float* __restrict__ eb) {
  int row = blockIdx.x;
  int b = (row / KSc) % Bc;
  int s0 = spans1[row * 2], s1 = spans1[row * 2 + 1];
  const float* x0 = x + ((size_t)b * Sc + s0) * Hc;
  const float* x1 = x + ((size_t)b * Sc + s1) * Hc;
  float* er = eb + (size_t)row * Hc;
  for (int h = threadIdx.x; h < Hc; h += 256) er[h] = 0.5f * (x0[h] + x1[h]);
}

// ---------------- s_k_w: tiled GEMM eb[256x768] @ W_s^T + b, masked ----------------
__global__ __launch_bounds__(256) void k_skw(const float* __restrict__ eb,
                                             const float* __restrict__ Wmats,
                                             const float* __restrict__ Wbias,
                                             const int* __restrict__ valid1,
                                             float* __restrict__ skw) {
  int m0 = blockIdx.y * 32;
  int n0 = blockIdx.x * 64;
  __shared__ float Asl[32][36];
  __shared__ float Bsl[32][68];
  int tid = threadIdx.x;
  int arow = tid >> 3, acol = (tid & 7) << 2;
  int brow = tid >> 2, bcol = (tid & 3) << 2;
  int txi = tid & 15, tyi = tid >> 4;
  const float* ap = eb + (size_t)(m0 + arow) * Hc + acol;
  const float* bp = Wmats + (size_t)(n0 + brow) * Hc + bcol;
  int nb = n0 + txi * 4;
  float4 bias = *(const float4*)&Wbias[nb];
  float acc[2][4];
#pragma unroll
  for (int i = 0; i < 2; ++i) { acc[i][0] = bias.x; acc[i][1] = bias.y; acc[i][2] = bias.z; acc[i][3] = bias.w; }
  for (int k0 = 0; k0 < Hc; k0 += 32) {
    float4 av = *(const float4*)(ap + k0);
    float4 b0 = *(const float4*)(bp + k0);
    float4 b1 = *(const float4*)(bp + k0 + 16);
    __syncthreads();
    Asl[acol + 0][arow] = av.x; Asl[acol + 1][arow] = av.y; Asl[acol + 2][arow] = av.z; Asl[acol + 3][arow] = av.w;
    Bsl[bcol + 0][brow] = b0.x; Bsl[bcol + 1][brow] = b0.y; Bsl[bcol + 2][brow] = b0.z; Bsl[bcol + 3][brow] = b0.w;
    Bsl[bcol + 16][brow] = b1.x; Bsl[bcol + 17][brow] = b1.y; Bsl[bcol + 18][brow] = b1.z; Bsl[bcol + 19][brow] = b1.w;
    __syncthreads();
#pragma unroll
    for (int kk = 0; kk < 32; ++kk) {
      float a0 = Asl[kk][tyi * 2], a1 = Asl[kk][tyi * 2 + 1];
      float4 b = *(const float4*)&Bsl[kk][txi * 4];
      acc[0][0] = fmaf(a0, b.x, acc[0][0]); acc[0][1] = fmaf(a0, b.y, acc[0][1]);
      acc[0][2] = fmaf(a0, b.z, acc[0][2]); acc[0][3] = fmaf(a0, b.w, acc[0][3]);
      acc[1][0] = fmaf(a1, b.x, acc[1][0]); acc[1][1] = fmaf(a1, b.y, acc[1][1]);
      acc[1][2] = fmaf(a1, b.z, acc[1][2]); acc[1][3] = fmaf(a1, b.w, acc[1][3]);
    }
  }
  int m_ = m0 + tyi * 2;
#pragma unroll
  for (int i = 0; i < 2; ++i) {
    int v = valid1[m_ + i];
    float4 o;
    o.x = v ? acc[i][0] : 0.f; o.y = v ? acc[i][1] : 0.f;
    o.z = v ? acc[i][2] : 0.f; o.w = v ? acc[i][3] : 0.f;
    *(float4*)&skw[(size_t)(m_ + i) * Hc + nb] = o;
  }
}

// ---------------- tg/tr: batched tiled GEMM over 4 groups ----------------
__global__ __launch_bounds__(256) void k_tgtr(const float* __restrict__ hg,
                                              const float* __restrict__ rel,
                                              const float* __restrict__ brel,
                                              const float* __restrict__ Wmats,
                                              const float* __restrict__ Wbias,
                                              float* __restrict__ tg,
                                              float* __restrict__ tr) {
  int grp = blockIdx.z;
  const float* Asrc; int M; int wsel; float* dst;
  if (grp == 0)      { Asrc = hg;   M = 8;  wsel = 2; dst = tg; }
  else if (grp == 1) { Asrc = hg;   M = 8;  wsel = 5; dst = tg + 8 * Hc; }
  else if (grp == 2) { Asrc = rel;  M = 40; wsel = 1; dst = tr; }
  else               { Asrc = brel; M = 40; wsel = 4; dst = tr + 40 * Hc; }
  int m0 = blockIdx.y * 32;
  if (m0 >= M) return;
  int n0 = blockIdx.x * 64;
  const float* W = Wmats + (size_t)wsel * Hc * Hc;
  const float* bias = Wbias + wsel * Hc;
  __shared__ float Asl[32][36];
  __shared__ float Bsl[32][68];
  int tid = threadIdx.x;
  int arow = tid >> 3, acol = (tid & 7) << 2;
  int brow = tid >> 2, bcol = (tid & 3) << 2;
  int txi = tid & 15, tyi = tid >> 4;
  int ar = m0 + arow;
  const float* ap = Asrc + (size_t)(ar < M ? ar : 0) * Hc + acol;
  const float* bp = W + (size_t)(n0 + brow) * Hc + bcol;
  int nb = n0 + txi * 4;
  float4 bv = *(const float4*)&bias[nb];
  float acc[2][4];
#pragma unroll
  for (int i = 0; i < 2; ++i) { acc[i][0] = bv.x; acc[i][1] = bv.y; acc[i][2] = bv.z; acc[i][3] = bv.w; }
  for (int k0 = 0; k0 < Hc; k0 += 32) {
    float4 av = *(const float4*)(ap + k0);
    float4 b0 = *(const float4*)(bp + k0);
    float4 b1 = *(const float4*)(bp + k0 + 16);
    __syncthreads();
    Asl[acol + 0][arow] = av.x; Asl[acol + 1][arow] = av.y; Asl[acol + 2][arow] = av.z; Asl[acol + 3][arow] = av.w;
    Bsl[bcol + 0][brow] = b0.x; Bsl[bcol + 1][brow] = b0.y; Bsl[bcol + 2][brow] = b0.z; Bsl[bcol + 3][brow] = b0.w;
    Bsl[bcol + 16][brow] = b1.x; Bsl[bcol + 17][brow] = b1.y; Bsl[bcol + 18][brow] = b1.z; Bsl[bcol + 19][brow] = b1.w;
    __syncthreads();
#pragma unroll
    for (int kk = 0; kk < 32; ++kk) {
      float a0 = Asl[kk][tyi * 2], a1 = Asl[kk][tyi * 2 + 1];
      float4 b = *(const float4*)&Bsl[kk][txi * 4];
      acc[0][0] = fmaf(a0, b.x, acc[0][0]); acc[0][1] = fmaf(a0, b.y, acc[0][1]);
      acc[0][2] = fmaf(a0, b.z, acc[0][2]); acc[0][3] = fmaf(a0, b.w, acc[0][3]);
      acc[1][0] = fmaf(a1, b.x, acc[1][0]); acc[1][1] = fmaf(a1, b.y, acc[1][1]);
      acc[1][2] = fmaf(a1, b.z, acc[1][2]); acc[1][3] = fmaf(a1, b.w, acc[1][3]);
    }
  }
  int m_ = m0 + tyi * 2;
#pragma unroll
  for (int i = 0; i < 2; ++i) {
    if (m_ + i < M) {
      float4 o; o.x = acc[i][0]; o.y = acc[i][1]; o.z = acc[i][2]; o.w = acc[i][3];
      *(float4*)&dst[(size_t)(m_ + i) * Hc + nb] = o;
    }
  }
}

// ---------------- big GEMM: 128x128 tile, 8x8/thread, full K, no bias ----------
// Grouped-pad LDS (stride-12 groups): reads & writes <=2-way bank aliasing.
// r8-validated numerics (k ascending per output). Output = x@W.T (bias in k_v).
__global__ __launch_bounds__(256) void k_tx2(const float* __restrict__ x,
                                             const float* __restrict__ Wmats,
                                             float* __restrict__ txo) {
  int dir = blockIdx.z;
  const float* W = Wmats + (size_t)(dir ? 6 : 3) * Hc * Hc;
  float* outp = txo + (size_t)dir * BSH;
  int m0 = blockIdx.y * 128;
  int n0 = blockIdx.x * 128;
  __shared__ float Asl[16 * 192];  // [kk][g*12 + i], g=row/8, i=row%8
  __shared__ float Bsl[16 * 192];
  int tid = threadIdx.x;
  int txi = tid & 15, tyi = tid >> 4;
  int sr = tid >> 1, skq = (tid & 1) * 8;   // staging: row 0..127, k-offset 0/8
  const float* xp = x + (size_t)(m0 + sr) * Hc + skq;
  const float* wp = W + (size_t)(n0 + sr) * Hc + skq;
  float* awp = &Asl[(sr >> 3) * 12 + (sr & 7)];
  float* bwp = &Bsl[(sr >> 3) * 12 + (sr & 7)];
  const float* arp = &Asl[tyi * 12];
  const float* brp = &Bsl[txi * 12];
  float4 a0 = *(const float4*)(xp);
  float4 a1 = *(const float4*)(xp + 4);
  float4 b0 = *(const float4*)(wp);
  float4 b1 = *(const float4*)(wp + 4);
  float acc[8][8] = {};
  const int NT = 48;  // 768/16
  for (int kt = 0; kt < NT; ++kt) {
    __syncthreads();
    awp[(skq + 0) * 192] = a0.x; awp[(skq + 1) * 192] = a0.y; awp[(skq + 2) * 192] = a0.z; awp[(skq + 3) * 192] = a0.w;
    awp[(skq + 4) * 192] = a1.x; awp[(skq + 5) * 192] = a1.y; awp[(skq + 6) * 192] = a1.z; awp[(skq + 7) * 192] = a1.w;
    bwp[(skq + 0) * 192] = b0.x; bwp[(skq + 1) * 192] = b0.y; bwp[(skq + 2) * 192] = b0.z; bwp[(skq + 3) * 192] = b0.w;
    bwp[(skq + 4) * 192] = b1.x; bwp[(skq + 5) * 192] = b1.y; bwp[(skq + 6) * 192] = b1.z; bwp[(skq + 7) * 192] = b1.w;
    __syncthreads();
    if (kt + 1 < NT) {
      int ko = (kt + 1) * 16;
      a0 = *(const float4*)(xp + ko);
      a1 = *(const float4*)(xp + ko + 4);
      b0 = *(const float4*)(wp + ko);
      b1 = *(const float4*)(wp + ko + 4);
    }
#pragma unroll
    for (int kk = 0; kk < 16; ++kk) {
      float4 A0 = *(const float4*)&arp[kk * 192];
      float4 A1 = *(const float4*)&arp[kk * 192 + 4];
      float4 B0 = *(const float4*)&brp[kk * 192];
      float4 B1 = *(const float4*)&brp[kk * 192 + 4];
      float aF[8] = {A0.x, A0.y, A0.z, A0.w, A1.x, A1.y, A1.z, A1.w};
      float bF[8] = {B0.x, B0.y, B0.z, B0.w, B1.x, B1.y, B1.z, B1.w};
#pragma unroll
      for (int i = 0; i < 8; ++i)
#pragma unroll
        for (int j = 0; j < 8; ++j)
          acc[i][j] = fmaf(aF[i], bF[j], acc[i][j]);
    }
  }
#pragma unroll
  for (int i = 0; i < 8; ++i) {
    float* orow = outp + (size_t)(m0 + tyi * 8 + i) * Hc + n0 + txi * 8;
    float4 o0, o1;
    o0.x = acc[i][0]; o0.y = acc[i][1]; o0.z = acc[i][2]; o0.w = acc[i][3];
    o1.x = acc[i][4]; o1.y = acc[i][5]; o1.z = acc[i][6]; o1.w = acc[i][7];
    *(float4*)orow = o0;
    *(float4*)(orow + 4) = o1;
  }
}

// ---------------- v[b,s,r] = sum_h tanh((tx+bias)+tg+tr)*Vw + Vb ----------------
// r-split x2 for occupancy (2048 blocks = 8/CU); log2e prescaled; W-bias added
// here with same association as before: (acc+bias) then +tg.
__global__ __launch_bounds__(256) void k_v(const float* __restrict__ txo,
                                           const float* __restrict__ Wbias,
                                           const float* __restrict__ tg,
                                           const float* __restrict__ tr,
                                           const float* __restrict__ Vw,
                                           const float* __restrict__ Vb,
                                           float* __restrict__ va) {
  const float Cl = 2.8853900817779268f;  // 2*log2(e)
  int id = blockIdx.x;            // dir*1024 + sb*2 + rhalf
  int dir = id >> 10;
  int rem = id & 1023;
  int rhalf = rem & 1;
  int bs0 = (rem >> 1) * 4;
  int b = bs0 >> 8;
  int tid = threadIdx.x;
  int wv = tid >> 6, lane = tid & 63;
  const float* tgr = tg + (dir * Bc + b) * Hc;
  const float* wb = Wbias + (dir ? 6 : 3) * Hc;
  float xt[4][12], vw[12];
#pragma unroll
  for (int u = 0; u < 12; ++u) {
    int h = lane + 64 * u;
    vw[u] = Vw[h];
    float wbv = wb[h];
    float tgv = tgr[h];
#pragma unroll
    for (int si = 0; si < 4; ++si) {
      float tv = txo[((size_t)dir * (Bc * Sc) + bs0 + si) * Hc + h] + wbv;
      xt[si][u] = (tv + tgv) * Cl;
    }
  }
  float vb0 = Vb[0];
  for (int q = 0; q < 5; ++q) {
    int r = rhalf * 20 + wv * 5 + q;
    const float* trr = tr + ((size_t)dir * Rc + r) * Hc + lane;
    float p0 = 0.f, p1 = 0.f, p2 = 0.f, p3 = 0.f;
#pragma unroll
    for (int u = 0; u < 12; ++u) {
      float t = trr[64 * u] * Cl;
      float e0 = __builtin_amdgcn_exp2f(xt[0][u] + t);
      float e1 = __builtin_amdgcn_exp2f(xt[1][u] + t);
      float e2 = __builtin_amdgcn_exp2f(xt[2][u] + t);
      float e3 = __builtin_amdgcn_exp2f(xt[3][u] + t);
      p0 = fmaf(fmaf(-2.f, __builtin_amdgcn_rcpf(e0 + 1.f), 1.f), vw[u], p0);
      p1 = fmaf(fmaf(-2.f, __builtin_amdgcn_rcpf(e1 + 1.f), 1.f), vw[u], p1);
      p2 = fmaf(fmaf(-2.f, __builtin_amdgcn_rcpf(e2 + 1.f), 1.f), vw[u], p2);
      p3 = fmaf(fmaf(-2.f, __builtin_amdgcn_rcpf(e3 + 1.f), 1.f), vw[u], p3);
    }
    p0 = wave_reduce_f(p0); p1 = wave_reduce_f(p1);
    p2 = wave_reduce_f(p2); p3 = wave_reduce_f(p3);
    if (lane == 0) {
      size_t base = ((size_t)dir * (Bc * Sc) + bs0) * Rc + r;
      va[base] = p0 + vb0;
      va[base + Rc] = p1 + vb0;
      va[base + 2 * Rc] = p2 + vb0;
      va[base + 3 * Rc] = p3 + vb0;
    }
  }
}

// ---------------- softmax over s per (dir,b,r) ----------------
__global__ __launch_bounds__(256) void k_softmax(float* __restrict__ va) {
  int id = blockIdx.x;
  int dir = id / (Bc * Rc); int rem = id % (Bc * Rc);
  int b = rem / Rc; int r = rem % Rc;
  int s = threadIdx.x;
  float* base = va + (((size_t)dir * Bc + b) * Sc) * Rc + r;
  float v = base[(size_t)s * Rc];
  __shared__ float red[8];
  float m = v;
#pragma unroll
  for (int o = 32; o; o >>= 1) m = fmaxf(m, __shfl_xor(m, o, 64));
  if ((s & 63) == 0) red[s >> 6] = m;
  __syncthreads();
  if (s == 0) red[4] = fmaxf(fmaxf(red[0], red[1]), fmaxf(red[2], red[3]));
  __syncthreads();
  m = red[4];
  float e = expf(v - m);
  float t = e;
#pragma unroll
  for (int o = 32; o; o >>= 1) t += __shfl_xor(t, o, 64);
  __syncthreads();
  if ((s & 63) == 0) red[s >> 6] = t;
  __syncthreads();
  if (s == 0) red[4] = red[0] + red[1] + red[2] + red[3];
  __syncthreads();
  base[(size_t)s * Rc] = e / red[4];
}

// ---------------- C partials: Cm4[p][dir,b][r][h], r-split x2 -> 128 blocks ----
__global__ __launch_bounds__(256, 1) void k_C(const float* __restrict__ va,
                                              const float* __restrict__ x,
                                              float* __restrict__ Cm4) {
  int id = blockIdx.x;   // (g*4 + p)*2 + rr
  int rr = id & 1;
  int p = (id >> 1) & 3;
  int g = id >> 3;       // 0..15
  int b = g & 7;
  __shared__ float As_[64 * Rc];
  int tid = threadIdx.x;
  const float* vab = va + ((size_t)g * Sc + p * 64) * Rc;
  for (int idx = tid; idx < 64 * Rc; idx += 256) As_[idx] = vab[idx];
  __syncthreads();
  const float* xb = x + ((size_t)b * Sc + p * 64) * Hc;
  float acc[3][20];
#pragma unroll
  for (int j = 0; j < 3; ++j)
#pragma unroll
    for (int r = 0; r < 20; ++r) acc[j][r] = 0.f;
  int rbase = rr * 20;
  for (int s = 0; s < 64; ++s) {
    float xv0 = xb[(size_t)s * Hc + tid];
    float xv1 = xb[(size_t)s * Hc + 256 + tid];
    float xv2 = xb[(size_t)s * Hc + 512 + tid];
#pragma unroll
    for (int q = 0; q < 5; ++q) {
      float4 a4 = *(const float4*)&As_[s * Rc + rbase + q * 4];
      acc[0][q * 4 + 0] = fmaf(a4.x, xv0, acc[0][q * 4 + 0]);
      acc[0][q * 4 + 1] = fmaf(a4.y, xv0, acc[0][q * 4 + 1]);
      acc[0][q * 4 + 2] = fmaf(a4.z, xv0, acc[0][q * 4 + 2]);
      acc[0][q * 4 + 3] = fmaf(a4.w, xv0, acc[0][q * 4 + 3]);
      acc[1][q * 4 + 0] = fmaf(a4.x, xv1, acc[1][q * 4 + 0]);
      acc[1][q * 4 + 1] = fmaf(a4.y, xv1, acc[1][q * 4 + 1]);
      acc[1][q * 4 + 2] = fmaf(a4.z, xv1, acc[1][q * 4 + 2]);
      acc[1][q * 4 + 3] = fmaf(a4.w, xv1, acc[1][q * 4 + 3]);
      acc[2][q * 4 + 0] = fmaf(a4.x, xv2, acc[2][q * 4 + 0]);
      acc[2][q * 4 + 1] = fmaf(a4.y, xv2, acc[2][q * 4 + 1]);
      acc[2][q * 4 + 2] = fmaf(a4.z, xv2, acc[2][q * 4 + 2]);
      acc[2][q * 4 + 3] = fmaf(a4.w, xv2, acc[2][q * 4 + 3]);
    }
  }
#pragma unroll
  for (int r = 0; r < 20; ++r) {
    size_t base = ((size_t)(p * 16 + g) * Rc + rbase + r) * Hc + tid;
    Cm4[base] = acc[0][r];
    Cm4[base + 256] = acc[1][r];
    Cm4[base + 512] = acc[2][r];
  }
}

// ---------------- ts, trl, c4 (f64 dots; trl sums 4 Cm partials) ----------------
__global__ __launch_bounds__(256) void k_tsc(const float* __restrict__ skw,
                                             const float* __restrict__ Cm4,
                                             const float* __restrict__ head_w,
                                             const float* __restrict__ Wbias,
                                             double* __restrict__ ts,
                                             double* __restrict__ trl,
                                             double* __restrict__ c4) {
  int wave = blockIdx.x * 4 + (threadIdx.x >> 6);
  int lane = threadIdx.x & 63;
  const float* src; const float* w; double* dst;
  bool partial4 = false;
  if (wave < 512) {
    int p = wave >> 7, rem = wave & 127;
    int b = rem >> 4, k = rem & 15, dir = p >> 1;
    src = skw + (((size_t)(dir * Bc + b)) * KSc + k) * Hc;
    w = head_w + (4 + p) * Hc;
    dst = ts + (p * Bc + b) * KSc + k;
  } else if (wave < 1792) {
    int q = wave - 512;
    int p = q / 320, rem = q % 320;
    int b = rem / Rc, r = rem % Rc, dir = p >> 1;
    src = Cm4 + ((size_t)(dir * Bc + b) * Rc + r) * Hc;
    w = head_w + (4 + p) * Hc;
    dst = trl + (p * Bc + b) * Rc + r;
    partial4 = true;
  } else if (wave < 1796) {
    int p = wave - 1792;
    src = Wbias + 7 * Hc;
    w = head_w + (4 + p) * Hc;
    dst = c4 + p;
  } else return;
  double acc = 0.0;
  if (partial4) {
    for (int h = lane; h < Hc; h += 64) {
      double cs = (double)src[h] + (double)src[h + CM_PS] +
                  (double)src[h + 2 * CM_PS] + (double)src[h + 3 * CM_PS];
      acc += cs * (double)w[h];
    }
  } else {
    for (int h = lane; h < Hc; h += 64) acc += (double)src[h] * (double)w[h];
  }
  acc = wave_reduce_d(acc);
  if (lane == 0) *dst = acc;
}

// ---------------- probs output [4,B,S,K,R] ----------------
__global__ __launch_bounds__(256) void k_probs(const double* __restrict__ tt,
                                               const double* __restrict__ ts,
                                               const double* __restrict__ trl,
                                               const double* __restrict__ c4,
                                               const float* __restrict__ head_b,
                                               float* __restrict__ out) {
  int id = blockIdx.x;
  int b = id >> 8, s = id & 255;
  (void)s;
  __shared__ double tsb[4][KSc];
  __shared__ double trb[4][Rc];
  __shared__ double basep[4];
  int tid = threadIdx.x;
  if (tid < 64) { int p = tid >> 4, k = tid & 15; tsb[p][k] = ts[(p * Bc + b) * KSc + k]; }
  if (tid < 160) { int p = tid / Rc, r = tid % Rc; trb[p][r] = trl[(p * Bc + b) * Rc + r]; }
  if (tid < 4) basep[tid] = tt[tid * (Bc * Sc) + id] + c4[tid] + (double)head_b[4 + tid];
  __syncthreads();
#pragma unroll
  for (int p = 0; p < 4; ++p) {
    double base = basep[p];
    float* op = out + ((size_t)(p * Bc) * Sc + id) * (KSc * Rc);
    for (int kr = tid; kr < KSc * Rc; kr += 256) {
      int k = kr / Rc, r = kr - k * Rc;
      double l = base + tsb[p][k] + trb[p][r];
      op[kr] = 1.f / (1.f + expf(-(float)l));
    }
  }
}

// ---------------- second-level greedy (10240 rows) ----------------
__global__ __launch_bounds__(256) void k_greedy2(const double* __restrict__ tt,
                                                 const double* __restrict__ ts,
                                                 const double* __restrict__ trl,
                                                 const double* __restrict__ c4,
                                                 const float* __restrict__ head_b,
                                                 const int* __restrict__ valid1,
                                                 float* __restrict__ out) {
  int gid = blockIdx.x * blockDim.x + threadIdx.x;
  if (gid >= 2 * Bc * KSc * Rc) return;
  int dir = gid / (Bc * KSc * Rc);
  int rem = gid % (Bc * KSc * Rc);
  int b = rem / (KSc * Rc);
  int kr = rem % (KSc * Rc);
  int k = kr / Rc, r = kr % Rc;
  int p0 = dir * 2, p1 = p0 + 1;
  double off0 = ts[(p0 * Bc + b) * KSc + k] + trl[(p0 * Bc + b) * Rc + r] + c4[p0] + (double)head_b[4 + p0];
  double off1 = ts[(p1 * Bc + b) * KSc + k] + trl[(p1 * Bc + b) * Rc + r] + c4[p1] + (double)head_b[4 + p1];
  const double* t0 = tt + p0 * (Bc * Sc) + b * Sc;
  const double* t1 = tt + p1 * (Bc * Sc) + b * Sc;
  uint64_t spm[4], epm[4], used[4] = {0, 0, 0, 0};
#pragma unroll
  for (int w = 0; w < 4; ++w) {
    uint64_t ms = 0, me = 0;
    for (int bit = 0; bit < 64; ++bit) {
      int s = w * 64 + bit;
      if (t0[s] + off0 > 0.0) ms |= (1ull << bit);
      if (t1[s] + off1 > 0.0) me |= (1ull << bit);
    }
    spm[w] = ms; epm[w] = me;
  }
  float* osp = out + (dir ? OUT_WSP : OUT_FSP) + (size_t)rem * KOc * 2;
  float* ova = out + (dir ? OUT_WVA : OUT_FVA) + (size_t)rem * KOc;
  for (int o = 0; o < KOc; ++o) { osp[o * 2] = 0.f; osp[o * 2 + 1] = 0.f; ova[o] = 0.f; }
  float sval = valid1[(dir * Bc + b) * KSc + k] ? 1.f : 0.f;
  int cnt = 0;
  for (int w = 0; w < 4; ++w) {
    uint64_t g = spm[w];
    while (g) {
      int bit = __ffsll((unsigned long long)g) - 1;
      g &= g - 1;
      int i = w * 64 + bit;
      int j = find_first(epm, used, i);
      if (j < 0) continue;
      used[j >> 6] |= (1ull << (j & 63));
      if (cnt < KOc) { osp[cnt * 2] = (float)i; osp[cnt * 2 + 1] = (float)j; ova[cnt] = sval; }
      cnt++;
    }
  }
}

extern "C" void kernel_launch(void* const* d_in, const int* in_sizes, int n_in,
                              void* d_out, int out_size, void* d_ws, size_t ws_size,
                              hipStream_t stream) {
  (void)in_sizes; (void)n_in; (void)out_size; (void)ws_size;
  const float* x = (const float*)d_in[0];
  const float* hg = (const float*)d_in[1];
  const float* rel = (const float*)d_in[2];
  const float* brt = (const float*)d_in[3];
  const float* head_w = (const float*)d_in[4];
  const float* head_b = (const float*)d_in[5];
  const float* Wmats = (const float*)d_in[6];
  const float* Wbias = (const float*)d_in[7];
  const float* rproj_w = (const float*)d_in[8];
  const float* rproj_b = (const float*)d_in[9];
  const float* Vw = (const float*)d_in[10];
  const float* Vb = (const float*)d_in[11];
  float* out = (float*)d_out;
  char* ws = (char*)d_ws;

  double* hv  = (double*)(ws + 0);          // 4*768 dbl
  double* c4  = (double*)(ws + 24576);      // 4 dbl
  double* tt  = (double*)(ws + 24608);      // 4*2048 dbl
  double* ts  = (double*)(ws + 90144);      // 4*128 dbl
  double* trl = (double*)(ws + 94240);      // 4*320 dbl
  float* l03  = (float*)(ws + 104480);      // 4*2048
  float* brel = (float*)(ws + 137248);      // 40*768
  float* tg   = (float*)(ws + 260128);      // 2*8*768
  float* tr   = (float*)(ws + 309280);      // 2*40*768
  float* txb  = (float*)(ws + 555040);      // 2*2048*768 (12.6 MB)
  float* va   = (float*)(ws + 13137952);    // 2*2048*40
  float* skw  = (float*)(ws + 15759392);    // 2*8*16*768
  int* spans1 = (int*)(ws + 16545824);      // 2*8*16*2
  int* valid1 = (int*)(ws + 16547872);      // 2*8*16
  float* eb   = txb;   // e-matrix [256][768]; dead once tx written
  float* Cm4  = txb;   // C partials [4][16][40][768]; tx dead after k_v

  k_prep0<<<132, 256, 0, stream>>>(brt, rproj_w, rproj_b, Wmats, head_w, brel, hv);
  k_l03tt<<<512, 256, 0, stream>>>(x, head_w, head_b, hv, l03, tt);
  k_greedy1<<<16, 64, 0, stream>>>(l03, spans1, valid1, out);
  k_egather<<<256, 256, 0, stream>>>(x, spans1, eb);
  k_skw<<<dim3(12, 8), 256, 0, stream>>>(eb, Wmats, Wbias, valid1, skw);
  k_tgtr<<<dim3(12, 2, 4), 256, 0, stream>>>(hg, rel, brel, Wmats, Wbias, tg, tr);
  k_tx2<<<dim3(6, 16, 2), 256, 0, stream>>>(x, Wmats, txb);
  k_v<<<2048, 256, 0, stream>>>(txb, Wbias, tg, tr, Vw, Vb, va);
  k_softmax<<<640, 256, 0, stream>>>(va);
  k_C<<<128, 256, 0, stream>>>(va, x, Cm4);
  k_tsc<<<449, 256, 0, stream>>>(skw, Cm4, head_w, Wbias, ts, trl, c4);
  k_probs<<<2048, 256, 0, stream>>>(tt, ts, trl, c4, head_b, out);
  k_greedy2<<<40, 256, 0, stream>>>(tt, ts, trl, c4, head_b, valid1, out);
}

// Round 11
// 309.847 us; speedup vs baseline: 1.1657x; 1.1657x over previous
//
#include <hip/hip_runtime.h>
#include <hip/hip_bf16.h>
#include <stdint.h>

// Problem dims
#define Bc 8
#define Sc 256
#define Hc 768
#define Rc 40
#define Tc 80
#define KSc 16
#define KOc 8

// Output offsets (float elements)
#define OUT_SSP 5242880
#define OUT_SVA 5243136
#define OUT_BSP 5243264
#define OUT_BVA 5243520
#define OUT_FSP 5243648
#define OUT_FVA 5325568
#define OUT_WSP 5366528
#define OUT_WVA 5448448

// Cm partial stride (p index): 16 groups * Rc * Hc
#define CM_PS (16 * Rc * Hc)
#define BSH (Bc * Sc * Hc)

__device__ inline double wave_reduce_d(double v) {
#pragma unroll
  for (int o = 32; o; o >>= 1) v += __shfl_down(v, o, 64);
  return v;
}
__device__ inline float wave_reduce_f(float v) {
#pragma unroll
  for (int o = 32; o; o >>= 1) v += __shfl_down(v, o, 64);
  return v;
}

// ---------------- prep0: hv (12 blk) + brel (120 blk) ----------------
__global__ __launch_bounds__(256) void k_prep0(const float* __restrict__ brt,
                                               const float* __restrict__ rw,
                                               const float* __restrict__ rb,
                                               const float* __restrict__ Wmats,
                                               const float* __restrict__ head_w,
                                               float* __restrict__ brel,
                                               double* __restrict__ hv) {
  int bb = blockIdx.x;
  int tid = threadIdx.x;
  if (bb < 12) {           // hv_i = h_i + W7^T h_i (f64)
    int idx = bb * 256 + tid;
    int i = idx / Hc, j = idx % Hc;
    const float* h4 = head_w + (4 + i) * Hc;
    const float* W7 = Wmats + (size_t)7 * Hc * Hc;
    double acc = (double)h4[j];
    for (int hh = 0; hh < Hc; ++hh)
      acc += (double)W7[(size_t)hh * Hc + j] * (double)h4[hh];
    hv[idx] = acc;
  } else {                 // brel [R,T]->[R,H]
    int idx = (bb - 12) * 256 + tid;
    int r = idx / Hc, h = idx % Hc;
    float acc = rb[h];
    const float* a = brt + r * Tc;
    const float* w = rw + (size_t)h * Tc;
    for (int t = 0; t < Tc; ++t) acc = fmaf(a[t], w[t], acc);
    brel[idx] = acc;
  }
}

// ---------------- fused l03 + tt: 8 f64 dots per token row ----------------
__global__ __launch_bounds__(256) void k_l03tt(const float* __restrict__ x,
                                               const float* __restrict__ head_w,
                                               const float* __restrict__ head_b,
                                               const double* __restrict__ hv,
                                               float* __restrict__ l03,
                                               double* __restrict__ tt) {
  int bs = blockIdx.x * 4 + (threadIdx.x >> 6);
  int lane = threadIdx.x & 63;
  if (bs >= Bc * Sc) return;
  const float* xr = x + (size_t)bs * Hc;
  double acc[8] = {0, 0, 0, 0, 0, 0, 0, 0};
  for (int h = lane; h < Hc; h += 64) {
    double xv = (double)xr[h];
    acc[0] += xv * (double)head_w[h];
    acc[1] += xv * (double)head_w[Hc + h];
    acc[2] += xv * (double)head_w[2 * Hc + h];
    acc[3] += xv * (double)head_w[3 * Hc + h];
    acc[4] += xv * hv[h];
    acc[5] += xv * hv[Hc + h];
    acc[6] += xv * hv[2 * Hc + h];
    acc[7] += xv * hv[3 * Hc + h];
  }
#pragma unroll
  for (int i = 0; i < 4; ++i) {
    double a = wave_reduce_d(acc[i]);
    if (lane == 0) l03[i * (Bc * Sc) + bs] = (float)(a + (double)head_b[i]);
  }
#pragma unroll
  for (int i = 0; i < 4; ++i) {
    double a = wave_reduce_d(acc[4 + i]);
    if (lane == 0) tt[i * (Bc * Sc) + bs] = a;
  }
}

// ---------------- greedy helpers ----------------
__device__ inline int find_first(const uint64_t* epm, const uint64_t* used, int i) {
  int wi = i >> 6;
  uint64_t m = epm[wi] & ~used[wi] & (~0ull << (i & 63));
  if (m) return (wi << 6) + (__ffsll((unsigned long long)m) - 1);
  for (int w = wi + 1; w < 4; ++w) {
    uint64_t mm = epm[w] & ~used[w];
    if (mm) return (w << 6) + (__ffsll((unsigned long long)mm) - 1);
  }
  return -1;
}

// ---------------- first-level greedy: 16 blocks (dir,b), wave-parallel masks ----------------
__global__ __launch_bounds__(64) void k_greedy1(const float* __restrict__ l03,
                                                int* __restrict__ spans1, int* __restrict__ valid1,
                                                float* __restrict__ out) {
  int t = blockIdx.x;  // 0..15
  int dir = t >> 3, b = t & 7;
  int lane = threadIdx.x;
  const float* sp = l03 + (dir * 2) * (Bc * Sc) + b * Sc;
  const float* ep = sp + Bc * Sc;
  uint64_t spm[4], epm[4];
#pragma unroll
  for (int w = 0; w < 4; ++w) {
    spm[w] = __ballot(sp[w * 64 + lane] > 0.f);
    epm[w] = __ballot(ep[w * 64 + lane] > 0.f);
  }
  __shared__ int ssp0[KSc], ssp1[KSc], sva[KSc];
  if (lane < KSc) { ssp0[lane] = 0; ssp1[lane] = 0; sva[lane] = 0; }
  __syncthreads();
  if (lane == 0) {
    uint64_t used[4] = {0, 0, 0, 0};
    int cnt = 0;
#pragma unroll
    for (int w = 0; w < 4; ++w) {
      uint64_t g = spm[w];
      while (g) {
        int bit = __ffsll((unsigned long long)g) - 1;
        g &= g - 1;
        int i = w * 64 + bit;
        int j = find_first(epm, used, i);
        if (j < 0) continue;
        used[j >> 6] |= (1ull << (j & 63));
        if (cnt < KSc) { ssp0[cnt] = i; ssp1[cnt] = j; sva[cnt] = 1; }
        cnt++;
      }
    }
  }
  __syncthreads();
  int base = (dir * Bc + b) * KSc;
  float* osp = out + (dir ? OUT_BSP : OUT_SSP) + b * KSc * 2;
  float* ova = out + (dir ? OUT_BVA : OUT_SVA) + b * KSc;
  if (lane < KSc) {
    spans1[(base + lane) * 2] = ssp0[lane];
    spans1[(base + lane) * 2 + 1] = ssp1[lane];
    valid1[base + lane] = sva[lane];
    osp[lane * 2] = (float)ssp0[lane];
    osp[lane * 2 + 1] = (float)ssp1[lane];
    ova[lane] = (float)sva[lane];
  }
}

// ---------------- e-gather: eb[row][h] = 0.5*(x[s0]+x[s1]) ----------------
__global__ __launch_bounds__(256) void k_egather(const float* __restrict__ x,
                                                 const int* __restrict__ spans1,
                                                 float* __restrict__ eb) {
  int row = blockIdx.x;
  int b = (row / KSc) % Bc;
  int s0 = spans1[row * 2], s1 = spans1[row * 2 + 1];
  const float* x0 = x + ((size_t)b * Sc + s0) * Hc;
  const float* x1 = x + ((size_t)b * Sc + s1) * Hc;
  float* er = eb + (size_t)row * Hc;
  for (int h = threadIdx.x; h < Hc; h += 256) er[h] = 0.5f * (x0[h] + x1[h]);
}

// ---------------- merged small GEMMs: skw (96 blk) + tg/tr (72 blk) -------------
// Identical tiled loop as prior k_skw/k_tgtr -> bitwise identical outputs.
__global__ __launch_bounds__(256) void k_small(const float* __restrict__ eb,
                                               const float* __restrict__ hg,
                                               const float* __restrict__ rel,
                                               const float* __restrict__ brel,
                                               const float* __restrict__ Wmats,
                                               const float* __restrict__ Wbias,
                                               const int* __restrict__ valid1,
                                               float* __restrict__ skw,
                                               float* __restrict__ tg,
                                               float* __restrict__ tr) {
  int bb = blockIdx.x;
  const float* Asrc; int M; int wsel; float* dst; int m0, n0; bool msk = false;
  if (bb < 96) {
    Asrc = eb; M = 256; wsel = 0; dst = skw; msk = true;
    m0 = (bb / 12) * 32; n0 = (bb % 12) * 64;
  } else {
    int q = bb - 96;
    if (q < 12)      { Asrc = hg;   M = 8;  wsel = 2; dst = tg;           m0 = 0; n0 = q * 64; }
    else if (q < 24) { Asrc = hg;   M = 8;  wsel = 5; dst = tg + 8 * Hc;  m0 = 0; n0 = (q - 12) * 64; }
    else if (q < 48) { int qq = q - 24; Asrc = rel;  M = 40; wsel = 1; dst = tr;           m0 = (qq / 12) * 32; n0 = (qq % 12) * 64; }
    else             { int qq = q - 48; Asrc = brel; M = 40; wsel = 4; dst = tr + 40 * Hc; m0 = (qq / 12) * 32; n0 = (qq % 12) * 64; }
  }
  const float* W = Wmats + (size_t)wsel * Hc * Hc;
  const float* bias = Wbias + wsel * Hc;
  __shared__ float Asl[32][36];
  __shared__ float Bsl[32][68];
  int tid = threadIdx.x;
  int arow = tid >> 3, acol = (tid & 7) << 2;
  int brow = tid >> 2, bcol = (tid & 3) << 2;
  int txi = tid & 15, tyi = tid >> 4;
  int ar = m0 + arow;
  const float* ap = Asrc + (size_t)(ar < M ? ar : 0) * Hc + acol;
  const float* bp = W + (size_t)(n0 + brow) * Hc + bcol;
  int nb = n0 + txi * 4;
  float4 bv = *(const float4*)&bias[nb];
  float acc[2][4];
#pragma unroll
  for (int i = 0; i < 2; ++i) { acc[i][0] = bv.x; acc[i][1] = bv.y; acc[i][2] = bv.z; acc[i][3] = bv.w; }
  for (int k0 = 0; k0 < Hc; k0 += 32) {
    float4 av = *(const float4*)(ap + k0);
    float4 b0 = *(const float4*)(bp + k0);
    float4 b1 = *(const float4*)(bp + k0 + 16);
    __syncthreads();
    Asl[acol + 0][arow] = av.x; Asl[acol + 1][arow] = av.y; Asl[acol + 2][arow] = av.z; Asl[acol + 3][arow] = av.w;
    Bsl[bcol + 0][brow] = b0.x; Bsl[bcol + 1][brow] = b0.y; Bsl[bcol + 2][brow] = b0.z; Bsl[bcol + 3][brow] = b0.w;
    Bsl[bcol + 16][brow] = b1.x; Bsl[bcol + 17][brow] = b1.y; Bsl[bcol + 18][brow] = b1.z; Bsl[bcol + 19][brow] = b1.w;
    __syncthreads();
#pragma unroll
    for (int kk = 0; kk < 32; ++kk) {
      float a0 = Asl[kk][tyi * 2], a1 = Asl[kk][tyi * 2 + 1];
      float4 b = *(const float4*)&Bsl[kk][txi * 4];
      acc[0][0] = fmaf(a0, b.x, acc[0][0]); acc[0][1] = fmaf(a0, b.y, acc[0][1]);
      acc[0][2] = fmaf(a0, b.z, acc[0][2]); acc[0][3] = fmaf(a0, b.w, acc[0][3]);
      acc[1][0] = fmaf(a1, b.x, acc[1][0]); acc[1][1] = fmaf(a1, b.y, acc[1][1]);
      acc[1][2] = fmaf(a1, b.z, acc[1][2]); acc[1][3] = fmaf(a1, b.w, acc[1][3]);
    }
  }
  int m_ = m0 + tyi * 2;
#pragma unroll
  for (int i = 0; i < 2; ++i) {
    int mrow = m_ + i;
    if (msk) {
      int v = valid1[mrow];
      float4 o;
      o.x = v ? acc[i][0] : 0.f; o.y = v ? acc[i][1] : 0.f;
      o.z = v ? acc[i][2] : 0.f; o.w = v ? acc[i][3] : 0.f;
      *(float4*)&dst[(size_t)mrow * Hc + nb] = o;
    } else if (mrow < M) {
      float4 o; o.x = acc[i][0]; o.y = acc[i][1]; o.z = acc[i][2]; o.w = acc[i][3];
      *(float4*)&dst[(size_t)mrow * Hc + nb] = o;
    }
  }
}

// ---------------- big GEMM (r4-proven): tx = x @ W.T + bias ----------------
#define BM 64
#define BN 64
#define BKK 32
#define LDP 68
__global__ __launch_bounds__(256) void k_tx(const float* __restrict__ x,
                                            const float* __restrict__ Wmats,
                                            const float* __restrict__ Wbias,
                                            float* __restrict__ txo) {
  int dir = blockIdx.z;
  const float* W = Wmats + (size_t)(dir ? 6 : 3) * Hc * Hc;
  const float* bias = Wbias + (dir ? 6 : 3) * Hc;
  float* outp = txo + (size_t)dir * BSH;
  int m0 = blockIdx.y * BM;
  int n0 = blockIdx.x * BN;
  __shared__ float Asl[BKK][LDP];
  __shared__ float Bsl[BKK][LDP];
  int tid = threadIdx.x;
  int lr = tid >> 2;
  int lc = (tid & 3) << 2;
  int txi = tid & 15, tyi = tid >> 4;
  const float* xp = x + (size_t)(m0 + lr) * Hc + lc;
  const float* wp = W + (size_t)(n0 + lr) * Hc + lc;
  float4 a0 = *(const float4*)(xp);
  float4 a1 = *(const float4*)(xp + 16);
  float4 b0 = *(const float4*)(wp);
  float4 b1 = *(const float4*)(wp + 16);
  float acc[4][4] = {};
  for (int k0 = 0; k0 < Hc; k0 += BKK) {
    __syncthreads();
    Asl[lc + 0][lr] = a0.x; Asl[lc + 1][lr] = a0.y; Asl[lc + 2][lr] = a0.z; Asl[lc + 3][lr] = a0.w;
    Asl[lc + 16][lr] = a1.x; Asl[lc + 17][lr] = a1.y; Asl[lc + 18][lr] = a1.z; Asl[lc + 19][lr] = a1.w;
    Bsl[lc + 0][lr] = b0.x; Bsl[lc + 1][lr] = b0.y; Bsl[lc + 2][lr] = b0.z; Bsl[lc + 3][lr] = b0.w;
    Bsl[lc + 16][lr] = b1.x; Bsl[lc + 17][lr] = b1.y; Bsl[lc + 18][lr] = b1.z; Bsl[lc + 19][lr] = b1.w;
    __syncthreads();
    if (k0 + BKK < Hc) {
      a0 = *(const float4*)(xp + k0 + BKK);
      a1 = *(const float4*)(xp + k0 + BKK + 16);
      b0 = *(const float4*)(wp + k0 + BKK);
      b1 = *(const float4*)(wp + k0 + BKK + 16);
    }
#pragma unroll
    for (int kk = 0; kk < BKK; ++kk) {
      float4 a = *(const float4*)&Asl[kk][tyi * 4];
      float4 b = *(const float4*)&Bsl[kk][txi * 4];
      acc[0][0] = fmaf(a.x, b.x, acc[0][0]); acc[0][1] = fmaf(a.x, b.y, acc[0][1]);
      acc[0][2] = fmaf(a.x, b.z, acc[0][2]); acc[0][3] = fmaf(a.x, b.w, acc[0][3]);
      acc[1][0] = fmaf(a.y, b.x, acc[1][0]); acc[1][1] = fmaf(a.y, b.y, acc[1][1]);
      acc[1][2] = fmaf(a.y, b.z, acc[1][2]); acc[1][3] = fmaf(a.y, b.w, acc[1][3]);
      acc[2][0] = fmaf(a.z, b.x, acc[2][0]); acc[2][1] = fmaf(a.z, b.y, acc[2][1]);
      acc[2][2] = fmaf(a.z, b.z, acc[2][2]); acc[2][3] = fmaf(a.z, b.w, acc[2][3]);
      acc[3][0] = fmaf(a.w, b.x, acc[3][0]); acc[3][1] = fmaf(a.w, b.y, acc[3][1]);
      acc[3][2] = fmaf(a.w, b.z, acc[3][2]); acc[3][3] = fmaf(a.w, b.w, acc[3][3]);
    }
  }
  int nb = n0 + txi * 4;
  float4 bb = *(const float4*)&bias[nb];
#pragma unroll
  for (int i2 = 0; i2 < 4; ++i2) {
    float4 o;
    o.x = acc[i2][0] + bb.x; o.y = acc[i2][1] + bb.y;
    o.z = acc[i2][2] + bb.z; o.w = acc[i2][3] + bb.w;
    *(float4*)&outp[(size_t)(m0 + tyi * 4 + i2) * Hc + nb] = o;
  }
}

// ---------------- v[b,s,r] = sum_h tanh(tx+tg+tr)*Vw + Vb ----------------
// r-split x2 for occupancy (2048 blocks = 8/CU); log2e prescaled.
__global__ __launch_bounds__(256) void k_v(const float* __restrict__ txo,
                                           const float* __restrict__ tg,
                                           const float* __restrict__ tr,
                                           const float* __restrict__ Vw,
                                           const float* __restrict__ Vb,
                                           float* __restrict__ va) {
  const float Cl = 2.8853900817779268f;  // 2*log2(e)
  int id = blockIdx.x;            // dir*1024 + sb*2 + rhalf
  int dir = id >> 10;
  int rem = id & 1023;
  int rhalf = rem & 1;
  int bs0 = (rem >> 1) * 4;
  int b = bs0 >> 8;
  int tid = threadIdx.x;
  int wv = tid >> 6, lane = tid & 63;
  const float* tgr = tg + (dir * Bc + b) * Hc;
  float xt[4][12], vw[12];
#pragma unroll
  for (int u = 0; u < 12; ++u) {
    int h = lane + 64 * u;
    vw[u] = Vw[h];
    float tgv = tgr[h];
#pragma unroll
    for (int si = 0; si < 4; ++si)
      xt[si][u] = (txo[((size_t)dir * (Bc * Sc) + bs0 + si) * Hc + h] + tgv) * Cl;
  }
  float vb0 = Vb[0];
  for (int q = 0; q < 5; ++q) {
    int r = rhalf * 20 + wv * 5 + q;
    const float* trr = tr + ((size_t)dir * Rc + r) * Hc + lane;
    float p0 = 0.f, p1 = 0.f, p2 = 0.f, p3 = 0.f;
#pragma unroll
    for (int u = 0; u < 12; ++u) {
      float t = trr[64 * u] * Cl;
      float e0 = __builtin_amdgcn_exp2f(xt[0][u] + t);
      float e1 = __builtin_amdgcn_exp2f(xt[1][u] + t);
      float e2 = __builtin_amdgcn_exp2f(xt[2][u] + t);
      float e3 = __builtin_amdgcn_exp2f(xt[3][u] + t);
      p0 = fmaf(fmaf(-2.f, __builtin_amdgcn_rcpf(e0 + 1.f), 1.f), vw[u], p0);
      p1 = fmaf(fmaf(-2.f, __builtin_amdgcn_rcpf(e1 + 1.f), 1.f), vw[u], p1);
      p2 = fmaf(fmaf(-2.f, __builtin_amdgcn_rcpf(e2 + 1.f), 1.f), vw[u], p2);
      p3 = fmaf(fmaf(-2.f, __builtin_amdgcn_rcpf(e3 + 1.f), 1.f), vw[u], p3);
    }
    p0 = wave_reduce_f(p0); p1 = wave_reduce_f(p1);
    p2 = wave_reduce_f(p2); p3 = wave_reduce_f(p3);
    if (lane == 0) {
      size_t base = ((size_t)dir * (Bc * Sc) + bs0) * Rc + r;
      va[base] = p0 + vb0;
      va[base + Rc] = p1 + vb0;
      va[base + 2 * Rc] = p2 + vb0;
      va[base + 3 * Rc] = p3 + vb0;
    }
  }
}

// ---------------- softmax over s per (dir,b,r) ----------------
__global__ __launch_bounds__(256) void k_softmax(float* __restrict__ va) {
  int id = blockIdx.x;
  int dir = id / (Bc * Rc); int rem = id % (Bc * Rc);
  int b = rem / Rc; int r = rem % Rc;
  int s = threadIdx.x;
  float* base = va + (((size_t)dir * Bc + b) * Sc) * Rc + r;
  float v = base[(size_t)s * Rc];
  __shared__ float red[8];
  float m = v;
#pragma unroll
  for (int o = 32; o; o >>= 1) m = fmaxf(m, __shfl_xor(m, o, 64));
  if ((s & 63) == 0) red[s >> 6] = m;
  __syncthreads();
  if (s == 0) red[4] = fmaxf(fmaxf(red[0], red[1]), fmaxf(red[2], red[3]));
  __syncthreads();
  m = red[4];
  float e = expf(v - m);
  float t = e;
#pragma unroll
  for (int o = 32; o; o >>= 1) t += __shfl_xor(t, o, 64);
  __syncthreads();
  if ((s & 63) == 0) red[s >> 6] = t;
  __syncthreads();
  if (s == 0) red[4] = red[0] + red[1] + red[2] + red[3];
  __syncthreads();
  base[(size_t)s * Rc] = e / red[4];
}

// ---------------- C partials: Cm4[p][dir,b][r][h], r-split x2 -> 128 blocks ----
__global__ __launch_bounds__(256, 1) void k_C(const float* __restrict__ va,
                                              const float* __restrict__ x,
                                              float* __restrict__ Cm4) {
  int id = blockIdx.x;   // (g*4 + p)*2 + rr
  int rr = id & 1;
  int p = (id >> 1) & 3;
  int g = id >> 3;       // 0..15
  int b = g & 7;
  __shared__ float As_[64 * Rc];
  int tid = threadIdx.x;
  const float* vab = va + ((size_t)g * Sc + p * 64) * Rc;
  for (int idx = tid; idx < 64 * Rc; idx += 256) As_[idx] = vab[idx];
  __syncthreads();
  const float* xb = x + ((size_t)b * Sc + p * 64) * Hc;
  float acc[3][20];
#pragma unroll
  for (int j = 0; j < 3; ++j)
#pragma unroll
    for (int r = 0; r < 20; ++r) acc[j][r] = 0.f;
  int rbase = rr * 20;
  for (int s = 0; s < 64; ++s) {
    float xv0 = xb[(size_t)s * Hc + tid];
    float xv1 = xb[(size_t)s * Hc + 256 + tid];
    float xv2 = xb[(size_t)s * Hc + 512 + tid];
#pragma unroll
    for (int q = 0; q < 5; ++q) {
      float4 a4 = *(const float4*)&As_[s * Rc + rbase + q * 4];
      acc[0][q * 4 + 0] = fmaf(a4.x, xv0, acc[0][q * 4 + 0]);
      acc[0][q * 4 + 1] = fmaf(a4.y, xv0, acc[0][q * 4 + 1]);
      acc[0][q * 4 + 2] = fmaf(a4.z, xv0, acc[0][q * 4 + 2]);
      acc[0][q * 4 + 3] = fmaf(a4.w, xv0, acc[0][q * 4 + 3]);
      acc[1][q * 4 + 0] = fmaf(a4.x, xv1, acc[1][q * 4 + 0]);
      acc[1][q * 4 + 1] = fmaf(a4.y, xv1, acc[1][q * 4 + 1]);
      acc[1][q * 4 + 2] = fmaf(a4.z, xv1, acc[1][q * 4 + 2]);
      acc[1][q * 4 + 3] = fmaf(a4.w, xv1, acc[1][q * 4 + 3]);
      acc[2][q * 4 + 0] = fmaf(a4.x, xv2, acc[2][q * 4 + 0]);
      acc[2][q * 4 + 1] = fmaf(a4.y, xv2, acc[2][q * 4 + 1]);
      acc[2][q * 4 + 2] = fmaf(a4.z, xv2, acc[2][q * 4 + 2]);
      acc[2][q * 4 + 3] = fmaf(a4.w, xv2, acc[2][q * 4 + 3]);
    }
  }
#pragma unroll
  for (int r = 0; r < 20; ++r) {
    size_t base = ((size_t)(p * 16 + g) * Rc + rbase + r) * Hc + tid;
    Cm4[base] = acc[0][r];
    Cm4[base + 256] = acc[1][r];
    Cm4[base + 512] = acc[2][r];
  }
}

// ---------------- ts, trl, c4 (f64 dots; trl sums 4 Cm partials) ----------------
__global__ __launch_bounds__(256) void k_tsc(const float* __restrict__ skw,
                                             const float* __restrict__ Cm4,
                                             const float* __restrict__ head_w,
                                             const float* __restrict__ Wbias,
                                             double* __restrict__ ts,
                                             double* __restrict__ trl,
                                             double* __restrict__ c4) {
  int wave = blockIdx.x * 4 + (threadIdx.x >> 6);
  int lane = threadIdx.x & 63;
  const float* src; const float* w; double* dst;
  bool partial4 = false;
  if (wave < 512) {
    int p = wave >> 7, rem = wave & 127;
    int b = rem >> 4, k = rem & 15, dir = p >> 1;
    src = skw + (((size_t)(dir * Bc + b)) * KSc + k) * Hc;
    w = head_w + (4 + p) * Hc;
    dst = ts + (p * Bc + b) * KSc + k;
  } else if (wave < 1792) {
    int q = wave - 512;
    int p = q / 320, rem = q % 320;
    int b = rem / Rc, r = rem % Rc, dir = p >> 1;
    src = Cm4 + ((size_t)(dir * Bc + b) * Rc + r) * Hc;
    w = head_w + (4 + p) * Hc;
    dst = trl + (p * Bc + b) * Rc + r;
    partial4 = true;
  } else if (wave < 1796) {
    int p = wave - 1792;
    src = Wbias + 7 * Hc;
    w = head_w + (4 + p) * Hc;
    dst = c4 + p;
  } else return;
  double acc = 0.0;
  if (partial4) {
    for (int h = lane; h < Hc; h += 64) {
      double cs = (double)src[h] + (double)src[h + CM_PS] +
                  (double)src[h + 2 * CM_PS] + (double)src[h + 3 * CM_PS];
      acc += cs * (double)w[h];
    }
  } else {
    for (int h = lane; h < Hc; h += 64) acc += (double)src[h] * (double)w[h];
  }
  acc = wave_reduce_d(acc);
  if (lane == 0) *dst = acc;
}

// ---------------- probs output [4,B,S,K,R], fast sigmoid ----------------
__global__ __launch_bounds__(256) void k_probs(const double* __restrict__ tt,
                                               const double* __restrict__ ts,
                                               const double* __restrict__ trl,
                                               const double* __restrict__ c4,
                                               const float* __restrict__ head_b,
                                               float* __restrict__ out) {
  const float L2E = 1.4426950408889634f;
  int id = blockIdx.x;
  int b = id >> 8, s = id & 255;
  (void)s;
  __shared__ double tsb[4][KSc];
  __shared__ double trb[4][Rc];
  __shared__ double basep[4];
  int tid = threadIdx.x;
  if (tid < 64) { int p = tid >> 4, k = tid & 15; tsb[p][k] = ts[(p * Bc + b) * KSc + k]; }
  if (tid < 160) { int p = tid / Rc, r = tid % Rc; trb[p][r] = trl[(p * Bc + b) * Rc + r]; }
  if (tid < 4) basep[tid] = tt[tid * (Bc * Sc) + id] + c4[tid] + (double)head_b[4 + tid];
  __syncthreads();
#pragma unroll
  for (int p = 0; p < 4; ++p) {
    double base = basep[p];
    float* op = out + ((size_t)(p * Bc) * Sc + id) * (KSc * Rc);
    for (int kr = tid; kr < KSc * Rc; kr += 256) {
      int k = kr / Rc, r = kr - k * Rc;
      float l = (float)(base + tsb[p][k] + trb[p][r]);
      float e = __builtin_amdgcn_exp2f(-L2E * l);
      op[kr] = __builtin_amdgcn_rcpf(1.f + e);
    }
  }
}

// ---------------- second-level greedy (10240 rows, 160x64 for CU spread) --------
__global__ __launch_bounds__(64) void k_greedy2(const double* __restrict__ tt,
                                                const double* __restrict__ ts,
                                                const double* __restrict__ trl,
                                                const double* __restrict__ c4,
                                                const float* __restrict__ head_b,
                                                const int* __restrict__ valid1,
                                                float* __restrict__ out) {
  int gid = blockIdx.x * 64 + threadIdx.x;
  if (gid >= 2 * Bc * KSc * Rc) return;
  int dir = gid / (Bc * KSc * Rc);
  int rem = gid % (Bc * KSc * Rc);
  int b = rem / (KSc * Rc);
  int kr = rem % (KSc * Rc);
  int k = kr / Rc, r = kr % Rc;
  int p0 = dir * 2, p1 = p0 + 1;
  double off0 = ts[(p0 * Bc + b) * KSc + k] + trl[(p0 * Bc + b) * Rc + r] + c4[p0] + (double)head_b[4 + p0];
  double off1 = ts[(p1 * Bc + b) * KSc + k] + trl[(p1 * Bc + b) * Rc + r] + c4[p1] + (double)head_b[4 + p1];
  const double* t0 = tt + p0 * (Bc * Sc) + b * Sc;
  const double* t1 = tt + p1 * (Bc * Sc) + b * Sc;
  uint64_t spm[4], epm[4], used[4] = {0, 0, 0, 0};
#pragma unroll
  for (int w = 0; w < 4; ++w) {
    uint64_t ms = 0, me = 0;
    for (int bit = 0; bit < 64; ++bit) {
      int s = w * 64 + bit;
      if (t0[s] + off0 > 0.0) ms |= (1ull << bit);
      if (t1[s] + off1 > 0.0) me |= (1ull << bit);
    }
    spm[w] = ms; epm[w] = me;
  }
  float* osp = out + (dir ? OUT_WSP : OUT_FSP) + (size_t)rem * KOc * 2;
  float* ova = out + (dir ? OUT_WVA : OUT_FVA) + (size_t)rem * KOc;
  for (int o = 0; o < KOc; ++o) { osp[o * 2] = 0.f; osp[o * 2 + 1] = 0.f; ova[o] = 0.f; }
  float sval = valid1[(dir * Bc + b) * KSc + k] ? 1.f : 0.f;
  int cnt = 0;
  for (int w = 0; w < 4; ++w) {
    uint64_t g = spm[w];
    while (g) {
      int bit = __ffsll((unsigned long long)g) - 1;
      g &= g - 1;
      int i = w * 64 + bit;
      int j = find_first(epm, used, i);
      if (j < 0) continue;
      used[j >> 6] |= (1ull << (j & 63));
      if (cnt < KOc) { osp[cnt * 2] = (float)i; osp[cnt * 2 + 1] = (float)j; ova[cnt] = sval; }
      cnt++;
    }
  }
}

extern "C" void kernel_launch(void* const* d_in, const int* in_sizes, int n_in,
                              void* d_out, int out_size, void* d_ws, size_t ws_size,
                              hipStream_t stream) {
  (void)in_sizes; (void)n_in; (void)out_size; (void)ws_size;
  const float* x = (const float*)d_in[0];
  const float* hg = (const float*)d_in[1];
  const float* rel = (const float*)d_in[2];
  const float* brt = (const float*)d_in[3];
  const float* head_w = (const float*)d_in[4];
  const float* head_b = (const float*)d_in[5];
  const float* Wmats = (const float*)d_in[6];
  const float* Wbias = (const float*)d_in[7];
  const float* rproj_w = (const float*)d_in[8];
  const float* rproj_b = (const float*)d_in[9];
  const float* Vw = (const float*)d_in[10];
  const float* Vb = (const float*)d_in[11];
  float* out = (float*)d_out;
  char* ws = (char*)d_ws;

  double* hv  = (double*)(ws + 0);          // 4*768 dbl
  double* c4  = (double*)(ws + 24576);      // 4 dbl
  double* tt  = (double*)(ws + 24608);      // 4*2048 dbl
  double* ts  = (double*)(ws + 90144);      // 4*128 dbl
  double* trl = (double*)(ws + 94240);      // 4*320 dbl
  float* l03  = (float*)(ws + 104480);      // 4*2048
  float* brel = (float*)(ws + 137248);      // 40*768
  float* tg   = (float*)(ws + 260128);      // 2*8*768
  float* tr   = (float*)(ws + 309280);      // 2*40*768
  float* txb  = (float*)(ws + 555040);      // 2*2048*768 (12.6 MB)
  float* va   = (float*)(ws + 13137952);    // 2*2048*40
  float* skw  = (float*)(ws + 15759392);    // 2*8*16*768
  int* spans1 = (int*)(ws + 16545824);      // 2*8*16*2
  int* valid1 = (int*)(ws + 16547872);      // 2*8*16
  float* eb   = txb;   // e-matrix [256][768]; dead once tx written
  float* Cm4  = txb;   // C partials [4][16][40][768]; tx dead after k_v

  k_prep0<<<132, 256, 0, stream>>>(brt, rproj_w, rproj_b, Wmats, head_w, brel, hv);
  k_l03tt<<<512, 256, 0, stream>>>(x, head_w, head_b, hv, l03, tt);
  k_greedy1<<<16, 64, 0, stream>>>(l03, spans1, valid1, out);
  k_egather<<<256, 256, 0, stream>>>(x, spans1, eb);
  k_small<<<168, 256, 0, stream>>>(eb, hg, rel, brel, Wmats, Wbias, valid1, skw, tg, tr);
  k_tx<<<dim3(12, 32, 2), 256, 0, stream>>>(x, Wmats, Wbias, txb);
  k_v<<<2048, 256, 0, stream>>>(txb, tg, tr, Vw, Vb, va);
  k_softmax<<<640, 256, 0, stream>>>(va);
  k_C<<<128, 256, 0, stream>>>(va, x, Cm4);
  k_tsc<<<449, 256, 0, stream>>>(skw, Cm4, head_w, Wbias, ts, trl, c4);
  k_probs<<<2048, 256, 0, stream>>>(tt, ts, trl, c4, head_b, out);
  k_greedy2<<<160, 64, 0, stream>>>(tt, ts, trl, c4, head_b, valid1, out);
}